// Round 2
// baseline (80.850 us; speedup 1.0000x reference)
//
#include <hip/hip_runtime.h>

#define N_IMG 8
#define CIN   128
#define H_IN  56
#define W_IN  56
#define COUT  128
#define HW    3136
#define KTOT  1152
#define BM    32          // pixels per workgroup
#define NIT   18          // 9 taps x 2 channel-halves (64 ch per iter)

typedef __attribute__((ext_vector_type(8))) short short8;
typedef __attribute__((ext_vector_type(4))) float f32x4;

__device__ __forceinline__ unsigned short f2b(float f) {
    unsigned u = __builtin_bit_cast(unsigned, f);
    u = u + 0x7FFFu + ((u >> 16) & 1u);
    return (unsigned short)(u >> 16);
}
__device__ __forceinline__ float b2f(unsigned short h) {
    unsigned u = ((unsigned)h) << 16;
    return __builtin_bit_cast(float, u);
}

// x (N,C,H,W) f32 -> xt (N,H,W,C) bf16
__global__ __launch_bounds__(256) void xpose_kernel(const float* __restrict__ x,
                                                    unsigned short* __restrict__ xt) {
    int tid = threadIdx.x;
    int c = tid & 127;
    int half = tid >> 7;
    int b = blockIdx.x;              // 8*98 = 784 blocks, 32 hw each
    int n = b / 98;
    int hw0 = (b - n * 98) * 32 + half * 16;
    const float* xp = x + ((size_t)(n * CIN + c)) * HW + hw0;
    unsigned short* op = xt + ((size_t)n * HW + hw0) * CIN + c;
#pragma unroll
    for (int r = 0; r < 16; ++r) op[r * CIN] = f2b(xp[r]);
}

// weight (COUT,CIN,3,3) f32 -> wr [COUT][kt*128+c] bf16
__global__ __launch_bounds__(256) void wprep_kernel(const float* __restrict__ w,
                                                    unsigned short* __restrict__ wr) {
    int idx = blockIdx.x * 256 + threadIdx.x;
    if (idx >= COUT * KTOT) return;
    int o = idx / KTOT;
    int r = idx - o * KTOT;
    int kt = r >> 7;
    int c = r & 127;
    wr[idx] = f2b(w[((size_t)o * CIN + c) * 9 + kt]);
}

__global__ __launch_bounds__(256) void deform_main(
    const float* __restrict__ offset, const float* __restrict__ x2,
    const float* __restrict__ bias, const unsigned short* __restrict__ xt,
    const unsigned short* __restrict__ wr, float* __restrict__ out)
{
    __shared__ int4   lin_lds[9 * BM];     // byte offsets of 4 corners
    __shared__ float4 wt_lds[9 * BM];      // 4 bilinear weights (0 when OOB)
    __shared__ short  a_lds[2][8][BM][8];  // [dbuf][k8][pixel][ch] -- conflict-free

    int tid = threadIdx.x;
    // XCD-aware swizzle: 784 = 8 * 98; each XCD owns exactly one image.
    int orig = blockIdx.x;
    int swz = (orig & 7) * 98 + (orig >> 3);
    int pix0 = swz * BM;
    int n = pix0 / HW;
    int hw0 = pix0 - n * HW;

    // ---- per-WG bilinear parameter stage: 288 = 9 taps x 32 pixels ----
    for (int i = tid; i < 9 * BM; i += 256) {
        int tap = i >> 5;
        int pl  = i & 31;
        int hw = hw0 + pl;
        int ho = hw / W_IN;
        int wo = hw - ho * W_IN;
        const float* offp = offset + ((size_t)n * 18 + tap * 2) * HW + hw;
        float offy = offp[0];
        float offx = offp[HW];
        int ki = tap / 3;
        int kj = tap - ki * 3;
        float py = (float)(ho - 1 + ki) + offy;
        float px = (float)(wo - 1 + kj) + offx;
        float y0f = floorf(py), x0f = floorf(px);
        float wy = py - y0f, wx = px - x0f;
        int y0 = (int)y0f, x0 = (int)x0f;
        int y1 = y0 + 1, x1 = x0 + 1;
        bool vy0 = (y0 >= 0) && (y0 < H_IN);
        bool vy1 = (y1 >= 0) && (y1 < H_IN);
        bool vx0 = (x0 >= 0) && (x0 < W_IN);
        bool vx1 = (x1 >= 0) && (x1 < W_IN);
        int cy0 = min(max(y0, 0), H_IN - 1), cy1 = min(max(y1, 0), H_IN - 1);
        int cx0 = min(max(x0, 0), W_IN - 1), cx1 = min(max(x1, 0), W_IN - 1);
        int4 lv;
        lv.x = (cy0 * W_IN + cx0) * (CIN * 2);
        lv.y = (cy0 * W_IN + cx1) * (CIN * 2);
        lv.z = (cy1 * W_IN + cx0) * (CIN * 2);
        lv.w = (cy1 * W_IN + cx1) * (CIN * 2);
        float4 wv;
        wv.x = (vy0 && vx0) ? (1.f - wy) * (1.f - wx) : 0.f;
        wv.y = (vy0 && vx1) ? (1.f - wy) * wx : 0.f;
        wv.z = (vy1 && vx0) ? wy * (1.f - wx) : 0.f;
        wv.w = (vy1 && vx1) ? wy * wx : 0.f;
        lin_lds[i] = lv;
        wt_lds[i] = wv;
    }
    __syncthreads();

    int lane  = tid & 63;
    int wv_id = tid >> 6;     // wave -> cout block of 32
    int llo = lane & 15;
    int lhi = lane >> 4;
    int pixel = tid & 31;     // A-build: 32 pixels x 8 channel groups
    int cg    = tid >> 5;
    const char* xbase = (const char*)(xt + (size_t)n * HW * CIN);

    f32x4 acc[2][2] = {};
    short8 g[4], gn[4];
    short8 bf[2][2], bn[2][2];

    auto do_gather = [&](int it, short8* gg) {
        int kt = it >> 1;
        int c0 = (it & 1) << 6;
        int4 lv = lin_lds[kt * BM + pixel];
        const char* base = xbase + (size_t)((c0 + cg * 8) * 2);
        gg[0] = *(const short8*)(base + lv.x);
        gg[1] = *(const short8*)(base + lv.y);
        gg[2] = *(const short8*)(base + lv.z);
        gg[3] = *(const short8*)(base + lv.w);
    };
    auto do_bload = [&](int it, short8 bb[2][2]) {
        int kt = it >> 1;
        int c0 = (it & 1) << 6;
#pragma unroll
        for (int n2 = 0; n2 < 2; ++n2)
#pragma unroll
            for (int kk = 0; kk < 2; ++kk)
                bb[n2][kk] = *(const short8*)(wr
                    + (size_t)(wv_id * 32 + n2 * 16 + llo) * KTOT
                    + kt * 128 + c0 + kk * 32 + lhi * 8);
    };
    auto interp_write = [&](int it, short8* gg) {
        int kt = it >> 1;
        float4 w4 = wt_lds[kt * BM + pixel];
        short8 av;
#pragma unroll
        for (int j = 0; j < 8; ++j) {
            float r = w4.x * b2f((unsigned short)gg[0][j])
                    + w4.y * b2f((unsigned short)gg[1][j])
                    + w4.z * b2f((unsigned short)gg[2][j])
                    + w4.w * b2f((unsigned short)gg[3][j]);
            av[j] = (short)f2b(r);
        }
        *(short8*)&a_lds[it & 1][cg][pixel][0] = av;
    };

    // prologue: fill buf0 + first B fragments
    do_gather(0, g);
    do_bload(0, bf);
    interp_write(0, g);
    __syncthreads();

#pragma unroll 2
    for (int it = 0; it < NIT; ++it) {
        if (it + 1 < NIT) {
            do_gather(it + 1, gn);   // issue loads early; consumed after MFMA
            do_bload(it + 1, bn);
        }
        int buf = it & 1;
        short8 a[2][2];
#pragma unroll
        for (int m = 0; m < 2; ++m)
#pragma unroll
            for (int kk = 0; kk < 2; ++kk)
                a[m][kk] = *(const short8*)&a_lds[buf][kk * 4 + lhi][m * 16 + llo][0];
#pragma unroll
        for (int m = 0; m < 2; ++m)
#pragma unroll
            for (int n2 = 0; n2 < 2; ++n2) {
                acc[m][n2] = __builtin_amdgcn_mfma_f32_16x16x32_bf16(a[m][0], bf[n2][0], acc[m][n2], 0, 0, 0);
                acc[m][n2] = __builtin_amdgcn_mfma_f32_16x16x32_bf16(a[m][1], bf[n2][1], acc[m][n2], 0, 0, 0);
            }
        if (it + 1 < NIT) interp_write(it + 1, gn);
        __syncthreads();
#pragma unroll
        for (int n2 = 0; n2 < 2; ++n2)
#pragma unroll
            for (int kk = 0; kk < 2; ++kk)
                bf[n2][kk] = bn[n2][kk];
    }

    // ---- epilogue: + bias + x2, ReLU, float4 stores ----
    float bv0 = bias[wv_id * 32 + llo];
    float bv1 = bias[wv_id * 32 + 16 + llo];
#pragma unroll
    for (int m = 0; m < 2; ++m) {
        int hw = hw0 + m * 16 + lhi * 4;
#pragma unroll
        for (int n2 = 0; n2 < 2; ++n2) {
            int cout = wv_id * 32 + n2 * 16 + llo;
            size_t off = ((size_t)n * COUT + cout) * HW + hw;
            f32x4 xv = *(const f32x4*)(x2 + off);
            float bb = n2 ? bv1 : bv0;
            f32x4 o;
#pragma unroll
            for (int r = 0; r < 4; ++r) {
                float v = acc[m][n2][r] + bb + xv[r];
                o[r] = v > 0.f ? v : 0.f;
            }
            *(f32x4*)(out + off) = o;
        }
    }
}

extern "C" void kernel_launch(void* const* d_in, const int* in_sizes, int n_in,
                              void* d_out, int out_size, void* d_ws, size_t ws_size,
                              hipStream_t stream) {
    const float* x      = (const float*)d_in[0];
    const float* offset = (const float*)d_in[1];
    const float* weight = (const float*)d_in[2];
    const float* bias   = (const float*)d_in[3];
    const float* x2     = (const float*)d_in[4];
    float* out = (float*)d_out;

    const size_t XT_BYTES = (size_t)N_IMG * HW * CIN * 2;   // 6,422,528
    unsigned short* xt = (unsigned short*)d_ws;
    unsigned short* wr = (unsigned short*)((char*)d_ws + XT_BYTES);

    xpose_kernel<<<784, 256, 0, stream>>>(x, xt);
    wprep_kernel<<<(COUT * KTOT + 255) / 256, 256, 0, stream>>>(weight, wr);
    deform_main<<<(N_IMG * HW) / BM, 256, 0, stream>>>(offset, x2, bias, xt, wr, out);
}

// Round 3
// 53.443 us; speedup vs baseline: 1.5128x; 1.5128x over previous
//
#include <hip/hip_runtime.h>

#define N_IMG 8
#define CIN   128
#define H_IN  56
#define W_IN  56
#define COUT  128
#define HW    3136
#define NSTEP 36      // 9 taps x 4 chunks of 32 channels

typedef __attribute__((ext_vector_type(8))) short short8;
typedef __attribute__((ext_vector_type(4))) float f32x4;

__device__ __forceinline__ unsigned short f2b(float f) {
    unsigned u = __builtin_bit_cast(unsigned, f);
    u = u + 0x7FFFu + ((u >> 16) & 1u);
    return (unsigned short)(u >> 16);
}
__device__ __forceinline__ float b2f(unsigned short h) {
    unsigned u = ((unsigned)h) << 16;
    return __builtin_bit_cast(float, u);
}
__device__ __forceinline__ void gload16(const void* g, void* l) {
    __builtin_amdgcn_global_load_lds(
        (const __attribute__((address_space(1))) unsigned int*)g,
        (__attribute__((address_space(3))) unsigned int*)l, 16, 0, 0);
}

// blocks 0..783: x (N,C,H,W) f32 -> xt (N,H,W,C) bf16
// blocks 784..855: weight -> wr_swz[step][frag][lane][8] bf16 (MFMA B-fragment-linear)
__global__ __launch_bounds__(256) void prep_kernel(const float* __restrict__ x,
                                                   const float* __restrict__ w,
                                                   unsigned short* __restrict__ xt,
                                                   unsigned short* __restrict__ wr) {
    int b = blockIdx.x;
    int tid = threadIdx.x;
    if (b < 784) {
        int c = tid & 127;
        int half = tid >> 7;
        int n = b / 98;
        int hw0 = (b - n * 98) * 32 + half * 16;
        const float* xp = x + ((size_t)(n * CIN + c)) * HW + hw0;
        unsigned short* op = xt + ((size_t)n * HW + hw0) * CIN + c;
#pragma unroll
        for (int r = 0; r < 16; ++r) op[r * CIN] = f2b(xp[r]);
    } else {
        int idx = (b - 784) * 256 + tid;        // 0..18431 = 36*8*64
        int lane = idx & 63;
        int f = (idx >> 6) & 7;
        int step = idx >> 9;
        int tap = step >> 2;
        int c0 = (step & 3) << 5;
        int cout = f * 16 + (lane & 15);
        int cb = c0 + (lane >> 4) * 8;
        short8 v;
#pragma unroll
        for (int j = 0; j < 8; ++j)
            v[j] = (short)f2b(w[((size_t)cout * CIN + cb + j) * 9 + tap]);
        *(short8*)(wr + (size_t)idx * 8) = v;
    }
}

__global__ __launch_bounds__(256) void deform_main(
    const float* __restrict__ offset, const float* __restrict__ x2,
    const float* __restrict__ bias, const unsigned short* __restrict__ xt,
    const unsigned short* __restrict__ wr, float* __restrict__ out)
{
    __shared__ int4   lin_lds[9 * 64];
    __shared__ float4 wt_lds[9 * 64];
    __shared__ short  bbuf[2][4096];   // double-buffered B step-tile, frag-linear

    int tid = threadIdx.x;
    int orig = blockIdx.x;                    // 392 = 8 * 49; one image per XCD
    int swz = (orig & 7) * 49 + (orig >> 3);
    int pix0 = swz * 64;
    int n = pix0 / HW;
    int hw0 = pix0 - n * HW;

    // ---- bilinear params for 64 pixels x 9 taps ----
    for (int i = tid; i < 9 * 64; i += 256) {
        int tap = i >> 6;
        int pl  = i & 63;
        int hw = hw0 + pl;
        int ho = hw / W_IN;
        int wo = hw - ho * W_IN;
        const float* offp = offset + ((size_t)n * 18 + tap * 2) * HW + hw;
        float offy = offp[0];
        float offx = offp[HW];
        int ki = tap / 3;
        int kj = tap - ki * 3;
        float py = (float)(ho - 1 + ki) + offy;
        float px = (float)(wo - 1 + kj) + offx;
        float y0f = floorf(py), x0f = floorf(px);
        float wy = py - y0f, wx = px - x0f;
        int y0 = (int)y0f, x0 = (int)x0f;
        int y1 = y0 + 1, x1 = x0 + 1;
        bool vy0 = (y0 >= 0) && (y0 < H_IN);
        bool vy1 = (y1 >= 0) && (y1 < H_IN);
        bool vx0 = (x0 >= 0) && (x0 < W_IN);
        bool vx1 = (x1 >= 0) && (x1 < W_IN);
        int cy0 = min(max(y0, 0), H_IN - 1), cy1 = min(max(y1, 0), H_IN - 1);
        int cx0 = min(max(x0, 0), W_IN - 1), cx1 = min(max(x1, 0), W_IN - 1);
        int4 lv;
        lv.x = (cy0 * W_IN + cx0) * (CIN * 2);
        lv.y = (cy0 * W_IN + cx1) * (CIN * 2);
        lv.z = (cy1 * W_IN + cx0) * (CIN * 2);
        lv.w = (cy1 * W_IN + cx1) * (CIN * 2);
        float4 wv;
        wv.x = (vy0 && vx0) ? (1.f - wy) * (1.f - wx) : 0.f;
        wv.y = (vy0 && vx1) ? (1.f - wy) * wx : 0.f;
        wv.z = (vy1 && vx0) ? wy * (1.f - wx) : 0.f;
        wv.w = (vy1 && vx1) ? wy * wx : 0.f;
        lin_lds[i] = lv;
        wt_lds[i] = wv;
    }
    __syncthreads();

    int lane = tid & 63, wv = tid >> 6;
    int llo = lane & 15, lhi = lane >> 4;
    int mypix = wv * 16 + llo;                 // wave's pixel for this lane
    const char* xb = (const char*)(xt + (size_t)n * HW * CIN);

    f32x4 acc[8] = {};
    short8 g1[4], g2[4];

    auto STAGE = [&](int it) {
        int buf = it & 1;
        const unsigned short* src = wr + (size_t)it * 4096 + wv * 1024 + lane * 8;
        short* dst = &bbuf[buf][wv * 1024];
        gload16(src, dst);
        gload16(src + 512, dst + 512);
    };
    auto GATHER = [&](int it, short8* g) {
        int tap = it >> 2;
        int c0 = (it & 3) << 5;
        int4 lv = lin_lds[tap * 64 + mypix];
        const char* bp = xb + ((c0 + lhi * 8) << 1);
        g[0] = *(const short8*)(bp + lv.x);
        g[1] = *(const short8*)(bp + lv.y);
        g[2] = *(const short8*)(bp + lv.z);
        g[3] = *(const short8*)(bp + lv.w);
    };
    auto STEP = [&](int it, short8* gc, short8* gn) {
        if (it + 1 < NSTEP) {
            STAGE(it + 1);
            GATHER(it + 1, gn);
        }
        // interp current gathers -> A fragment (regs), already in MFMA layout
        float4 w4 = wt_lds[(it >> 2) * 64 + mypix];
        short8 a;
#pragma unroll
        for (int j = 0; j < 8; ++j) {
            float r = w4.x * b2f((unsigned short)gc[0][j])
                    + w4.y * b2f((unsigned short)gc[1][j])
                    + w4.z * b2f((unsigned short)gc[2][j])
                    + w4.w * b2f((unsigned short)gc[3][j]);
            a[j] = (short)f2b(r);
        }
        const short* bb = &bbuf[it & 1][0];
#pragma unroll
        for (int f = 0; f < 8; ++f) {
            short8 bf = *(const short8*)(bb + f * 512 + lane * 8);
            acc[f] = __builtin_amdgcn_mfma_f32_16x16x32_bf16(a, bf, acc[f], 0, 0, 0);
        }
        __syncthreads();
    };

    // prologue: stage step 0, gather step 0
    STAGE(0);
    GATHER(0, g1);
    __syncthreads();

    for (int it = 0; it < NSTEP; it += 2) {
        STEP(it, g1, g2);
        STEP(it + 1, g2, g1);
    }

    // ---- epilogue: + bias + x2, ReLU, f32x4 stores (4 consecutive pixels) ----
    int hwbase = hw0 + wv * 16 + lhi * 4;
#pragma unroll
    for (int f = 0; f < 8; ++f) {
        int cout = f * 16 + llo;
        float bb = bias[cout];
        size_t off = ((size_t)(n * COUT + cout)) * HW + hwbase;
        f32x4 xv = *(const f32x4*)(x2 + off);
        f32x4 o;
#pragma unroll
        for (int r = 0; r < 4; ++r) {
            float v = acc[f][r] + bb + xv[r];
            o[r] = v > 0.f ? v : 0.f;
        }
        *(f32x4*)(out + off) = o;
    }
}

extern "C" void kernel_launch(void* const* d_in, const int* in_sizes, int n_in,
                              void* d_out, int out_size, void* d_ws, size_t ws_size,
                              hipStream_t stream) {
    const float* x      = (const float*)d_in[0];
    const float* offset = (const float*)d_in[1];
    const float* weight = (const float*)d_in[2];
    const float* bias   = (const float*)d_in[3];
    const float* x2     = (const float*)d_in[4];
    float* out = (float*)d_out;

    const size_t XT_BYTES = (size_t)N_IMG * HW * CIN * 2;   // 6,422,528
    unsigned short* xt = (unsigned short*)d_ws;
    unsigned short* wr = (unsigned short*)((char*)d_ws + XT_BYTES);

    prep_kernel<<<856, 256, 0, stream>>>(x, weight, xt, wr);
    deform_main<<<392, 256, 0, stream>>>(offset, x2, bias, xt, wr, out);
}